// Round 4
// baseline (1054.371 us; speedup 1.0000x reference)
//
#include <hip/hip_runtime.h>

#define NUSERS 100000
#define NITEMS 50000
#define NNODES 150000   // NUSERS + NITEMS
#define EMB 64
#define NEDGES 4800000
#define OUTC 192        // 3 * EMB concatenated output columns
#define NEG_SLOPE 0.01f

__device__ __forceinline__ unsigned short f2bf(float f) {
    unsigned u = __float_as_uint(f);
    unsigned r = (u + 0x7fffu + ((u >> 16) & 1u)) >> 16;   // RN-even
    return (unsigned short)r;
}

// ---------------- ego0 build: gather user/item embeddings into out cols 0:64
__global__ void build_ego(const int* __restrict__ ui, const int* __restrict__ ii,
                          const float* __restrict__ uemb, const float* __restrict__ iemb,
                          float* __restrict__ out) {
    int gid = blockIdx.x * blockDim.x + threadIdx.x;   // one float4 per thread
    int r = gid >> 4, p = gid & 15;
    if (r >= NNODES) return;
    const float* src = (r < NUSERS) ? (uemb + (size_t)ui[r] * EMB)
                                    : (iemb + (size_t)ii[r - NUSERS] * EMB);
    float4 v = ((const float4*)src)[p];
    *(float4*)(out + (size_t)r * OUTC + p * 4) = v;
}

// f32 (stride OUTC) -> compact bf16 [NNODES][64]
__global__ void conv_bf16(const float* __restrict__ src, unsigned short* __restrict__ dst) {
    int gid = blockIdx.x * blockDim.x + threadIdx.x;   // 4 dims per thread
    int r = gid >> 4, p = gid & 15;
    if (r >= NNODES) return;
    float4 v = *(const float4*)(src + (size_t)r * OUTC + p * 4);
    ushort4 o;
    o.x = f2bf(v.x); o.y = f2bf(v.y); o.z = f2bf(v.z); o.w = f2bf(v.w);
    *(ushort4*)(dst + (size_t)r * EMB + p * 4) = o;
}

// ---------------- CSR build ----------------
__global__ void count_pos(const int* __restrict__ rows, int* __restrict__ counts,
                          int* __restrict__ pos) {
    int gid = blockIdx.x * blockDim.x + threadIdx.x;
    if (gid < NEDGES) pos[gid] = atomicAdd(&counts[rows[gid]], 1);
}

__global__ void scan_chunk(const int* __restrict__ counts, int* __restrict__ rowptr,
                           int* __restrict__ blksum, int n) {
    __shared__ int buf[1024];
    int tid = threadIdx.x;
    int gid = blockIdx.x * 1024 + tid;
    int v = (gid < n) ? counts[gid] : 0;
    buf[tid] = v;
    __syncthreads();
    for (int off = 1; off < 1024; off <<= 1) {
        int t = (tid >= off) ? buf[tid - off] : 0;
        __syncthreads();
        buf[tid] += t;
        __syncthreads();
    }
    if (gid < n) rowptr[gid + 1] = buf[tid];
    if (tid == 1023) blksum[blockIdx.x] = buf[tid];
}

__global__ void scan_sums(int* __restrict__ blksum, int n) {
    __shared__ int buf[256];
    int tid = threadIdx.x;
    int v = (tid < n) ? blksum[tid] : 0;
    buf[tid] = v;
    __syncthreads();
    for (int off = 1; off < 256; off <<= 1) {
        int t = (tid >= off) ? buf[tid - off] : 0;
        __syncthreads();
        buf[tid] += t;
        __syncthreads();
    }
    if (tid < n) blksum[tid] = buf[tid] - v;  // exclusive
}

__global__ void add_offsets(int* __restrict__ rowptr, const int* __restrict__ blksum, int n) {
    int gid = blockIdx.x * 1024 + threadIdx.x;
    if (gid < n) rowptr[gid + 1] += blksum[blockIdx.x];
    if (gid == 0) rowptr[0] = 0;
}

__global__ void fill_csr(const int* __restrict__ rows, const int* __restrict__ cols,
                         const float* __restrict__ vals, const int* __restrict__ pos,
                         const int* __restrict__ rowptr, int2* __restrict__ csr) {
    int gid = blockIdx.x * blockDim.x + threadIdx.x;
    if (gid >= NEDGES) return;
    int r = rows[gid];
    int idx = rowptr[r] + pos[gid];
    csr[idx] = make_int2(cols[gid], __float_as_int(vals[gid]));
}

// ---------------- fused SpMM (bf16 gather) + dense layer ----------------
// one wave per row. Gather: 8 edge-subgroups x 8-lane dim groups; lane loads
// ushort8 (16B = 8 bf16 dims); 4 independent gathers in flight per lane.
// Epilogue f32: egoNew = LReLU(side@Wg^T+bg) + LReLU((ego*side)@Wb^T+bb).
#define ACC8(g, v)                                              \
    a0 = fmaf(v, __uint_as_float((g).x << 16), a0);             \
    a1 = fmaf(v, __uint_as_float((g).x & 0xffff0000u), a1);     \
    a2 = fmaf(v, __uint_as_float((g).y << 16), a2);             \
    a3 = fmaf(v, __uint_as_float((g).y & 0xffff0000u), a3);     \
    a4 = fmaf(v, __uint_as_float((g).z << 16), a4);             \
    a5 = fmaf(v, __uint_as_float((g).z & 0xffff0000u), a5);     \
    a6 = fmaf(v, __uint_as_float((g).w << 16), a6);             \
    a7 = fmaf(v, __uint_as_float((g).w & 0xffff0000u), a7);

__global__ __launch_bounds__(512) void spmm_fused(
        const int* __restrict__ rowptr, const int2* __restrict__ csr,
        const unsigned short* __restrict__ egoc,   // bf16 [NNODES][64]
        const float* __restrict__ egoPrev,         // f32, stride OUTC
        float* __restrict__ egoNew,                // f32, stride OUTC
        unsigned short* __restrict__ egocNew,      // bf16 [NNODES][64] or null
        const float* __restrict__ Wg, const float* __restrict__ bg,
        const float* __restrict__ Wb, const float* __restrict__ bb) {
    __shared__ float WgT[64 * 65];
    __shared__ float WbT[64 * 65];
    int tid = threadIdx.x;
    for (int i = tid; i < 4096; i += 512) {
        int r = i >> 6, c = i & 63;            // W[r][c]
        WgT[c * 65 + r] = Wg[i];
        WbT[c * 65 + r] = Wb[i];
    }
    __syncthreads();
    int lane = tid & 63;
    int row = blockIdx.x * 8 + (tid >> 6);
    if (row >= NNODES) return;

    float biasg = bg[lane], biasb = bb[lane];
    float eg = egoPrev[(size_t)row * OUTC + lane];    // issued early
    int s = rowptr[row], e = rowptr[row + 1];
    int esub = lane >> 3;        // edge subgroup 0..7
    int dg   = lane & 7;         // dim group: dims [8dg, 8dg+8)
    const uint4* egc = (const uint4*)egoc;
    float a0 = 0.f, a1 = 0.f, a2 = 0.f, a3 = 0.f,
          a4 = 0.f, a5 = 0.f, a6 = 0.f, a7 = 0.f;
    for (int base = s; base < e; base += 64) {
        int2 cv = make_int2(0, 0);
        if (base + lane < e) cv = csr[base + lane];
        int nb = e - base; if (nb > 64) nb = 64;
        int tMax = (nb + 31) >> 5;           // 32 edges per t-step
        for (int t = 0; t < tMax; ++t) {
            int b0 = 32 * t + esub;
            int c0 = __shfl(cv.x, b0);
            int c1 = __shfl(cv.x, b0 + 8);
            int c2 = __shfl(cv.x, b0 + 16);
            int c3 = __shfl(cv.x, b0 + 24);
            float v0 = __uint_as_float((unsigned)__shfl(cv.y, b0));
            float v1 = __uint_as_float((unsigned)__shfl(cv.y, b0 + 8));
            float v2 = __uint_as_float((unsigned)__shfl(cv.y, b0 + 16));
            float v3 = __uint_as_float((unsigned)__shfl(cv.y, b0 + 24));
            uint4 g0 = egc[(size_t)c0 * 8 + dg];
            uint4 g1 = egc[(size_t)c1 * 8 + dg];
            uint4 g2 = egc[(size_t)c2 * 8 + dg];
            uint4 g3 = egc[(size_t)c3 * 8 + dg];
            ACC8(g0, v0); ACC8(g1, v1); ACC8(g2, v2); ACC8(g3, v3);
        }
    }
    // reduce across the 8 edge-subgroups (lanes sharing dg differ in bits 3..5)
    #define RED(m) a0 += __shfl_xor(a0, m); a1 += __shfl_xor(a1, m); \
                   a2 += __shfl_xor(a2, m); a3 += __shfl_xor(a3, m); \
                   a4 += __shfl_xor(a4, m); a5 += __shfl_xor(a5, m); \
                   a6 += __shfl_xor(a6, m); a7 += __shfl_xor(a7, m);
    RED(8) RED(16) RED(32)
    #undef RED
    // redistribute: lane j wants dim j = elem (j&7) of chunk (j>>3), held by lane (j>>3)
    int srcl = lane >> 3;
    float t0 = __shfl(a0, srcl), t1 = __shfl(a1, srcl);
    float t2 = __shfl(a2, srcl), t3 = __shfl(a3, srcl);
    float t4 = __shfl(a4, srcl), t5 = __shfl(a5, srcl);
    float t6 = __shfl(a6, srcl), t7 = __shfl(a7, srcl);
    int e2 = lane & 7;
    float sv = t0;
    sv = (e2 == 1) ? t1 : sv; sv = (e2 == 2) ? t2 : sv;
    sv = (e2 == 3) ? t3 : sv; sv = (e2 == 4) ? t4 : sv;
    sv = (e2 == 5) ? t5 : sv; sv = (e2 == 6) ? t6 : sv;
    sv = (e2 == 7) ? t7 : sv;

    // dense epilogue: 4 split accumulators per output (dep chain 16)
    float p  = sv * eg;
    float ag0 = biasg, ag1 = 0.f, ag2 = 0.f, ag3 = 0.f;
    float ab0 = biasb, ab1 = 0.f, ab2 = 0.f, ab3 = 0.f;
    #pragma unroll
    for (int k = 0; k < 64; k += 4) {
        float sk0 = __shfl(sv, k),     pk0 = __shfl(p, k);
        float sk1 = __shfl(sv, k + 1), pk1 = __shfl(p, k + 1);
        float sk2 = __shfl(sv, k + 2), pk2 = __shfl(p, k + 2);
        float sk3 = __shfl(sv, k + 3), pk3 = __shfl(p, k + 3);
        ag0 = fmaf(sk0, WgT[(k)     * 65 + lane], ag0);
        ag1 = fmaf(sk1, WgT[(k + 1) * 65 + lane], ag1);
        ag2 = fmaf(sk2, WgT[(k + 2) * 65 + lane], ag2);
        ag3 = fmaf(sk3, WgT[(k + 3) * 65 + lane], ag3);
        ab0 = fmaf(pk0, WbT[(k)     * 65 + lane], ab0);
        ab1 = fmaf(pk1, WbT[(k + 1) * 65 + lane], ab1);
        ab2 = fmaf(pk2, WbT[(k + 2) * 65 + lane], ab2);
        ab3 = fmaf(pk3, WbT[(k + 3) * 65 + lane], ab3);
    }
    float accg = (ag0 + ag1) + (ag2 + ag3);
    float accb = (ab0 + ab1) + (ab2 + ab3);
    accg = (accg > 0.f) ? accg : NEG_SLOPE * accg;
    accb = (accb > 0.f) ? accb : NEG_SLOPE * accb;
    float nv = accg + accb;
    egoNew[(size_t)row * OUTC + lane] = nv;
    if (egocNew) egocNew[(size_t)row * EMB + lane] = f2bf(nv);
}

extern "C" void kernel_launch(void* const* d_in, const int* in_sizes, int n_in,
                              void* d_out, int out_size, void* d_ws, size_t ws_size,
                              hipStream_t stream) {
    const int*   ui   = (const int*)  d_in[0];
    const int*   ii   = (const int*)  d_in[1];
    const int*   rows = (const int*)  d_in[2];
    const int*   cols = (const int*)  d_in[3];
    const float* vals = (const float*)d_in[4];
    const float* uemb = (const float*)d_in[5];
    const float* iemb = (const float*)d_in[6];
    const float* Wg0 = (const float*)d_in[7],  *bg0 = (const float*)d_in[8];
    const float* Wb0 = (const float*)d_in[9],  *bb0 = (const float*)d_in[10];
    const float* Wg1 = (const float*)d_in[11], *bg1 = (const float*)d_in[12];
    const float* Wb1 = (const float*)d_in[13], *bb1 = (const float*)d_in[14];
    float* out = (float*)d_out;

    char* ws = (char*)d_ws;
    int2*  csr    = (int2*)ws; ws += (size_t)NEDGES * 8;                 // 38.4 MB
    char*  buf0   = ws;        ws += (size_t)NEDGES * 4;                 // 19.2 MB: pos, then egoc0
    unsigned short* egoc1 = (unsigned short*)ws; ws += (size_t)NNODES * EMB * 2; // 19.2 MB
    int*   rowptr = (int*) ws; ws += (size_t)(NNODES + 1) * 4;
    int*   counts = (int*) ws; ws += (size_t)NNODES * 4;
    int*   blksum = (int*) ws; ws += 256 * 4;
    int* pos = (int*)buf0;
    unsigned short* egoc0 = (unsigned short*)buf0;

    const int NBLK = (NNODES + 1023) / 1024;  // 147

    // ego0 -> out cols [0,64)
    build_ego<<<(NNODES * 16 + 255) / 256, 256, 0, stream>>>(ui, ii, uemb, iemb, out);

    // CSR build (once, reused for both layers)
    hipMemsetAsync(counts, 0, (size_t)NNODES * 4, stream);
    count_pos<<<(NEDGES + 255) / 256, 256, 0, stream>>>(rows, counts, pos);
    scan_chunk<<<NBLK, 1024, 0, stream>>>(counts, rowptr, blksum, NNODES);
    scan_sums<<<1, 256, 0, stream>>>(blksum, NBLK);
    add_offsets<<<NBLK, 1024, 0, stream>>>(rowptr, blksum, NNODES);
    fill_csr<<<(NEDGES + 255) / 256, 256, 0, stream>>>(rows, cols, vals, pos, rowptr, csr);

    // pos is dead now -> reuse as egoc0 (bf16 compact copy of ego0)
    conv_bf16<<<(NNODES * 16 + 255) / 256, 256, 0, stream>>>(out + 0, egoc0);

    // layer 0: ego1 -> out cols [64,128) + egoc1 bf16
    spmm_fused<<<(NNODES + 7) / 8, 512, 0, stream>>>(rowptr, csr, egoc0, out + 0,
                                                     out + 64, egoc1,
                                                     Wg0, bg0, Wb0, bb0);
    // layer 1: ego2 -> out cols [128,192)
    spmm_fused<<<(NNODES + 7) / 8, 512, 0, stream>>>(rowptr, csr, egoc1, out + 64,
                                                     out + 128, (unsigned short*)nullptr,
                                                     Wg1, bg1, Wb1, bb1);
}

// Round 5
// 610.482 us; speedup vs baseline: 1.7271x; 1.7271x over previous
//
#include <hip/hip_runtime.h>

#define NUSERS 100000
#define NITEMS 50000
#define NNODES 150000   // NUSERS + NITEMS
#define EMB 64
#define NEDGES 4800000
#define OUTC 192        // 3 * EMB concatenated output columns
#define NEG_SLOPE 0.01f

typedef __attribute__((ext_vector_type(8))) short bf16x8;
typedef __attribute__((ext_vector_type(4))) float f32x4;

__device__ __forceinline__ unsigned short f2bf(float f) {
    unsigned u = __float_as_uint(f);
    unsigned r = (u + 0x7fffu + ((u >> 16) & 1u)) >> 16;   // RN-even
    return (unsigned short)r;
}
__device__ __forceinline__ float bf2f(short s) {
    return __uint_as_float(((unsigned)(unsigned short)s) << 16);
}

// ---------------- ego0 build: gather user/item embeddings into out cols 0:64
__global__ void build_ego(const int* __restrict__ ui, const int* __restrict__ ii,
                          const float* __restrict__ uemb, const float* __restrict__ iemb,
                          float* __restrict__ out) {
    int gid = blockIdx.x * blockDim.x + threadIdx.x;   // one float4 per thread
    int r = gid >> 4, p = gid & 15;
    if (r >= NNODES) return;
    const float* src = (r < NUSERS) ? (uemb + (size_t)ui[r] * EMB)
                                    : (iemb + (size_t)ii[r - NUSERS] * EMB);
    float4 v = ((const float4*)src)[p];
    *(float4*)(out + (size_t)r * OUTC + p * 4) = v;
}

// f32 (stride OUTC) -> compact bf16 [NNODES][64]
__global__ void conv_bf16(const float* __restrict__ src, unsigned short* __restrict__ dst) {
    int gid = blockIdx.x * blockDim.x + threadIdx.x;   // 4 dims per thread
    int r = gid >> 4, p = gid & 15;
    if (r >= NNODES) return;
    float4 v = *(const float4*)(src + (size_t)r * OUTC + p * 4);
    ushort4 o;
    o.x = f2bf(v.x); o.y = f2bf(v.y); o.z = f2bf(v.z); o.w = f2bf(v.w);
    *(ushort4*)(dst + (size_t)r * EMB + p * 4) = o;
}

// f32 [64][64] -> bf16 [64][64]
__global__ void conv_w(const float* __restrict__ s, unsigned short* __restrict__ d) {
    int i = blockIdx.x * 256 + threadIdx.x;
    if (i < 4096) d[i] = f2bf(s[i]);
}

// ---------------- CSR build ----------------
__global__ void count_pos(const int* __restrict__ rows, int* __restrict__ counts,
                          int* __restrict__ pos) {
    int gid = blockIdx.x * blockDim.x + threadIdx.x;
    if (gid < NEDGES) pos[gid] = atomicAdd(&counts[rows[gid]], 1);
}

__global__ void scan_chunk(const int* __restrict__ counts, int* __restrict__ rowptr,
                           int* __restrict__ blksum, int n) {
    __shared__ int buf[1024];
    int tid = threadIdx.x;
    int gid = blockIdx.x * 1024 + tid;
    int v = (gid < n) ? counts[gid] : 0;
    buf[tid] = v;
    __syncthreads();
    for (int off = 1; off < 1024; off <<= 1) {
        int t = (tid >= off) ? buf[tid - off] : 0;
        __syncthreads();
        buf[tid] += t;
        __syncthreads();
    }
    if (gid < n) rowptr[gid + 1] = buf[tid];
    if (tid == 1023) blksum[blockIdx.x] = buf[tid];
}

__global__ void scan_sums(int* __restrict__ blksum, int n) {
    __shared__ int buf[256];
    int tid = threadIdx.x;
    int v = (tid < n) ? blksum[tid] : 0;
    buf[tid] = v;
    __syncthreads();
    for (int off = 1; off < 256; off <<= 1) {
        int t = (tid >= off) ? buf[tid - off] : 0;
        __syncthreads();
        buf[tid] += t;
        __syncthreads();
    }
    if (tid < n) blksum[tid] = buf[tid] - v;  // exclusive
}

__global__ void add_offsets(int* __restrict__ rowptr, const int* __restrict__ blksum, int n) {
    int gid = blockIdx.x * 1024 + threadIdx.x;
    if (gid < n) rowptr[gid + 1] += blksum[blockIdx.x];
    if (gid == 0) rowptr[0] = 0;
}

__global__ void fill_csr(const int* __restrict__ rows, const int* __restrict__ cols,
                         const float* __restrict__ vals, const int* __restrict__ pos,
                         const int* __restrict__ rowptr, int2* __restrict__ csr) {
    int gid = blockIdx.x * blockDim.x + threadIdx.x;
    if (gid >= NEDGES) return;
    int r = rows[gid];
    int idx = rowptr[r] + pos[gid];
    csr[idx] = make_int2(cols[gid], __float_as_int(vals[gid]));
}

// ---------------- gather-only SpMM: sideb = bf16( A @ egoc ) ----------------
// one row per 8-lane group; lane owns dims [8dg, 8dg+8). No cross-lane ops.
// 4 edges unrolled -> 4 independent uint4 gathers in flight per lane.
#define ACC8(g, v)                                              \
    a0 = fmaf(v, __uint_as_float((g).x << 16), a0);             \
    a1 = fmaf(v, __uint_as_float((g).x & 0xffff0000u), a1);     \
    a2 = fmaf(v, __uint_as_float((g).y << 16), a2);             \
    a3 = fmaf(v, __uint_as_float((g).y & 0xffff0000u), a3);     \
    a4 = fmaf(v, __uint_as_float((g).z << 16), a4);             \
    a5 = fmaf(v, __uint_as_float((g).z & 0xffff0000u), a5);     \
    a6 = fmaf(v, __uint_as_float((g).w << 16), a6);             \
    a7 = fmaf(v, __uint_as_float((g).w & 0xffff0000u), a7);

__global__ __launch_bounds__(512) void spmm_gather(
        const int* __restrict__ rowptr, const int2* __restrict__ csr,
        const unsigned short* __restrict__ egoc,   // bf16 [NNODES][64]
        unsigned short* __restrict__ sideb,        // bf16, row stride strideE ushorts
        int strideE) {
    int tid = blockIdx.x * blockDim.x + threadIdx.x;
    int row = tid >> 3;
    int dg  = tid & 7;
    if (row >= NNODES) return;
    int s = rowptr[row], e = rowptr[row + 1];
    const uint4* egc = (const uint4*)egoc;
    float a0 = 0.f, a1 = 0.f, a2 = 0.f, a3 = 0.f,
          a4 = 0.f, a5 = 0.f, a6 = 0.f, a7 = 0.f;
    for (int b = s; b < e; b += 4) {
        int i1 = b + 1 < e ? b + 1 : e - 1;
        int i2 = b + 2 < e ? b + 2 : e - 1;
        int i3 = b + 3 < e ? b + 3 : e - 1;
        int2 cv0 = csr[b], cv1 = csr[i1], cv2 = csr[i2], cv3 = csr[i3];
        float v0 = __int_as_float(cv0.y);
        float v1 = (b + 1 < e) ? __int_as_float(cv1.y) : 0.f;
        float v2 = (b + 2 < e) ? __int_as_float(cv2.y) : 0.f;
        float v3 = (b + 3 < e) ? __int_as_float(cv3.y) : 0.f;
        uint4 g0 = egc[(size_t)cv0.x * 8 + dg];
        uint4 g1 = egc[(size_t)cv1.x * 8 + dg];
        uint4 g2 = egc[(size_t)cv2.x * 8 + dg];
        uint4 g3 = egc[(size_t)cv3.x * 8 + dg];
        ACC8(g0, v0); ACC8(g1, v1); ACC8(g2, v2); ACC8(g3, v3);
    }
    uint p0 = (unsigned)f2bf(a0) | ((unsigned)f2bf(a1) << 16);
    uint p1 = (unsigned)f2bf(a2) | ((unsigned)f2bf(a3) << 16);
    uint p2 = (unsigned)f2bf(a4) | ((unsigned)f2bf(a5) << 16);
    uint p3 = (unsigned)f2bf(a6) | ((unsigned)f2bf(a7) << 16);
    uint4 st = make_uint4(p0, p1, p2, p3);
    *(uint4*)(sideb + (size_t)row * strideE + dg * 8) = st;
}

// ---------------- dense layer via MFMA ----------------
// out[r][c] = LReLU(sum_k side[r][k] Wg[c][k] + bg[c])
//           + LReLU(sum_k (ego[r][k]*side[r][k]) Wb[c][k] + bb[c])
// 16x16x32 bf16 MFMA, K=64 -> 2 MFMA per GEMM. Block = 4 waves = 4 col tiles.
__global__ __launch_bounds__(256) void dense_mfma(
        const unsigned short* __restrict__ sideb, int sStrideE,
        const unsigned short* __restrict__ egoc,   // bf16 [NNODES][64]
        const unsigned short* __restrict__ wg,     // bf16 [64][64] (row c, col k)
        const unsigned short* __restrict__ wb,
        const float* __restrict__ bg, const float* __restrict__ bb,
        float* __restrict__ outCol,                // f32, stride OUTC
        unsigned short* __restrict__ egocNew) {    // bf16 [NNODES][64] or null
    int lane = threadIdx.x & 63;
    int ct   = (threadIdx.x >> 6) * 16;       // col tile (wave id * 16)
    int rtile = blockIdx.x * 16;
    int ar = lane & 15, kg = lane >> 4;
    bf16x8 sfrag[2], pfrag[2], wgf[2], wbf[2];
    #pragma unroll
    for (int t = 0; t < 2; ++t) {
        int koff = kg * 8 + 32 * t;            // bf16 element offset in k
        bf16x8 sv = *(const bf16x8*)(sideb + (size_t)(rtile + ar) * sStrideE + koff);
        bf16x8 ev = *(const bf16x8*)(egoc  + (size_t)(rtile + ar) * EMB + koff);
        sfrag[t] = sv;
        bf16x8 pv;
        #pragma unroll
        for (int j = 0; j < 8; ++j)
            pv[j] = (short)f2bf(bf2f(sv[j]) * bf2f(ev[j]));
        pfrag[t] = pv;
        wgf[t] = *(const bf16x8*)(wg + (size_t)(ct + ar) * EMB + koff);
        wbf[t] = *(const bf16x8*)(wb + (size_t)(ct + ar) * EMB + koff);
    }
    f32x4 accg = {0.f, 0.f, 0.f, 0.f}, accb = {0.f, 0.f, 0.f, 0.f};
    accg = __builtin_amdgcn_mfma_f32_16x16x32_bf16(sfrag[0], wgf[0], accg, 0, 0, 0);
    accg = __builtin_amdgcn_mfma_f32_16x16x32_bf16(sfrag[1], wgf[1], accg, 0, 0, 0);
    accb = __builtin_amdgcn_mfma_f32_16x16x32_bf16(pfrag[0], wbf[0], accb, 0, 0, 0);
    accb = __builtin_amdgcn_mfma_f32_16x16x32_bf16(pfrag[1], wbf[1], accb, 0, 0, 0);
    int c = ct + ar;                            // C/D: col = lane&15
    float biasg = bg[c], biasb = bb[c];
    #pragma unroll
    for (int i = 0; i < 4; ++i) {
        int r = rtile + kg * 4 + i;             // C/D: row = (lane>>4)*4 + reg
        float g = accg[i] + biasg; g = (g > 0.f) ? g : NEG_SLOPE * g;
        float q = accb[i] + biasb; q = (q > 0.f) ? q : NEG_SLOPE * q;
        float nv = g + q;
        outCol[(size_t)r * OUTC + c] = nv;
        if (egocNew) egocNew[(size_t)r * EMB + c] = f2bf(nv);
    }
}

extern "C" void kernel_launch(void* const* d_in, const int* in_sizes, int n_in,
                              void* d_out, int out_size, void* d_ws, size_t ws_size,
                              hipStream_t stream) {
    const int*   ui   = (const int*)  d_in[0];
    const int*   ii   = (const int*)  d_in[1];
    const int*   rows = (const int*)  d_in[2];
    const int*   cols = (const int*)  d_in[3];
    const float* vals = (const float*)d_in[4];
    const float* uemb = (const float*)d_in[5];
    const float* iemb = (const float*)d_in[6];
    const float* Wg0 = (const float*)d_in[7],  *bg0 = (const float*)d_in[8];
    const float* Wb0 = (const float*)d_in[9],  *bb0 = (const float*)d_in[10];
    const float* Wg1 = (const float*)d_in[11], *bg1 = (const float*)d_in[12];
    const float* Wb1 = (const float*)d_in[13], *bb1 = (const float*)d_in[14];
    float* out = (float*)d_out;

    char* ws = (char*)d_ws;
    int2*  csr    = (int2*)ws; ws += (size_t)NEDGES * 8;                 // 38.4 MB
    char*  buf0   = ws;        ws += (size_t)NEDGES * 4;                 // 19.2 MB: pos -> egoc0 -> (L1 sideb reuse is separate)
    unsigned short* egoc1 = (unsigned short*)ws; ws += (size_t)NNODES * EMB * 2; // 19.2 MB
    int*   rowptr = (int*) ws; ws += (size_t)(NNODES + 1) * 4;
    int*   counts = (int*) ws; ws += (size_t)NNODES * 4;
    int*   blksum = (int*) ws; ws += 256 * 4;
    unsigned short* wgb0 = (unsigned short*)ws; ws += 4096 * 2;
    unsigned short* wbb0 = (unsigned short*)ws; ws += 4096 * 2;
    unsigned short* wgb1 = (unsigned short*)ws; ws += 4096 * 2;
    unsigned short* wbb1 = (unsigned short*)ws; ws += 4096 * 2;
    int* pos = (int*)buf0;
    unsigned short* egoc0 = (unsigned short*)buf0;

    const int NBLK = (NNODES + 1023) / 1024;  // 147

    // ego0 -> out cols [0,64)
    build_ego<<<(NNODES * 16 + 255) / 256, 256, 0, stream>>>(ui, ii, uemb, iemb, out);

    // CSR build
    hipMemsetAsync(counts, 0, (size_t)NNODES * 4, stream);
    count_pos<<<(NEDGES + 255) / 256, 256, 0, stream>>>(rows, counts, pos);
    scan_chunk<<<NBLK, 1024, 0, stream>>>(counts, rowptr, blksum, NNODES);
    scan_sums<<<1, 256, 0, stream>>>(blksum, NBLK);
    add_offsets<<<NBLK, 1024, 0, stream>>>(rowptr, blksum, NNODES);
    fill_csr<<<(NEDGES + 255) / 256, 256, 0, stream>>>(rows, cols, vals, pos, rowptr, csr);

    // pos dead -> egoc0 (bf16 compact ego0); bf16 weights
    conv_bf16<<<(NNODES * 16 + 255) / 256, 256, 0, stream>>>(out + 0, egoc0);
    conv_w<<<16, 256, 0, stream>>>(Wg0, wgb0);
    conv_w<<<16, 256, 0, stream>>>(Wb0, wbb0);
    conv_w<<<16, 256, 0, stream>>>(Wg1, wgb1);
    conv_w<<<16, 256, 0, stream>>>(Wb1, wbb1);

    // L0 sideb: stash bf16 side in out cols [128,192) region (row stride 768B, offset 512B)
    unsigned short* side0 = (unsigned short*)((char*)out + 512);
    const int SIDE0_STRIDE = 384;   // ushorts (= 768B)
    spmm_gather<<<(NNODES * 8 + 511) / 512, 512, 0, stream>>>(rowptr, csr, egoc0,
                                                              side0, SIDE0_STRIDE);
    dense_mfma<<<NNODES / 16, 256, 0, stream>>>(side0, SIDE0_STRIDE, egoc0,
                                                wgb0, wbb0, bg0, bb0,
                                                out + 64, egoc1);

    // L1 sideb: buf0 (egoc0 dead after L0 dense)
    unsigned short* side1 = (unsigned short*)buf0;
    spmm_gather<<<(NNODES * 8 + 511) / 512, 512, 0, stream>>>(rowptr, csr, egoc1,
                                                              side1, EMB);
    dense_mfma<<<NNODES / 16, 256, 0, stream>>>(side1, EMB, egoc1,
                                                wgb1, wbb1, bg1, bb1,
                                                out + 128, (unsigned short*)nullptr);
}